// Round 1
// baseline (160.455 us; speedup 1.0000x reference)
//
#include <hip/hip_runtime.h>

typedef _Float16 f16;
typedef _Float16 f16x4 __attribute__((ext_vector_type(4)));
typedef _Float16 f16x8 __attribute__((ext_vector_type(8)));
typedef float    f32x4 __attribute__((ext_vector_type(4)));

#define BATCH 65536
#define INDIM 512
#define MD    64
#define MSZ   100
#define NCAT  35
#define CKSZ  5
#define ODIM  512
#define N1    256   // X cols: [bq(64) | cq(64) | S_raw(100) | pad(28)]
#define KK2   288   // A2 cols: [attn(100) | cat slots(175) | pad(13)]

static __device__ __forceinline__ f32x4 mfma16(f16x4 a, f16x4 b, f32x4 c) {
  return __builtin_amdgcn_mfma_f32_16x16x16f16(a, b, c, 0, 0, 0);
}

// ---------------- prep 1: B1 [256][512] f16 (n-major) + bias1[256] f32 ----
// n<64: W_base ; n<128: W_cat ; n<228: Ws[:,m] = W_base^T @ l2norm(keys[m])
__global__ __launch_bounds__(256) void k_prep1(const float* __restrict__ Wb,
    const float* __restrict__ bb, const float* __restrict__ Wc,
    const float* __restrict__ bc, const float* __restrict__ keys,
    f16* __restrict__ B1, float* __restrict__ bias1) {
  int id = blockIdx.x * 256 + threadIdx.x;        // 256*512 total
  int k = id & (INDIM - 1);
  int n = id >> 9;
  float v = 0.f;
  if (n < 64) v = Wb[n * INDIM + k];
  else if (n < 128) v = Wc[(n - 64) * INDIM + k];
  else if (n < 128 + MSZ) {
    int m = n - 128;
    float s = 0.f;
    for (int d = 0; d < MD; d++) { float kv = keys[m * MD + d]; s += kv * kv; }
    float dn = fmaxf(sqrtf(s), 1e-8f);
    float a = 0.f;
    for (int d = 0; d < MD; d++) a += Wb[d * INDIM + k] * keys[m * MD + d];
    v = a / dn;
  }
  B1[n * INDIM + k] = (f16)v;
  if (k == 0) {
    float bv = 0.f;
    if (n < 64) bv = bb[n];
    else if (n < 128) bv = bc[n - 64];
    else if (n < 128 + MSZ) {
      int m = n - 128;
      float s = 0.f;
      for (int d = 0; d < MD; d++) { float kv = keys[m * MD + d]; s += kv * kv; }
      float dn = fmaxf(sqrtf(s), 1e-8f);
      float a = 0.f;
      for (int d = 0; d < MD; d++) a += bb[d] * keys[m * MD + d];
      bv = a / dn;
    }
    bias1[n] = bv;
  }
}

// ---------------- prep 2: B2T [512][288] f16 (o-major) ---------------------
// kk<100: V1[kk][o] = base_vals[kk]·W_out[o,:64] ; kk<275: C2 slot = cat_vals[s]·W_out[o,64:]
__global__ __launch_bounds__(256) void k_prep2(const float* __restrict__ bvals,
    const float* __restrict__ cvals, const float* __restrict__ Wo,
    f16* __restrict__ B2T) {
  int id = blockIdx.x * 256 + threadIdx.x;        // 512*288 total
  if (id >= ODIM * KK2) return;
  int kk = id % KK2;
  int o  = id / KK2;
  float v = 0.f;
  if (kk < MSZ) {
    for (int d = 0; d < MD; d++) v += bvals[kk * MD + d] * Wo[o * 128 + d];
  } else if (kk < MSZ + NCAT * CKSZ) {
    int s = kk - MSZ;
    for (int d = 0; d < MD; d++) v += cvals[s * MD + d] * Wo[o * 128 + 64 + d];
  }
  B2T[(size_t)o * KK2 + kk] = (f16)v;
}

// ---------------- GEMM1: X = query @ B1^T + bias1  (M=65536,K=512,N=256) ---
__global__ __launch_bounds__(512) void k_gemm1(const float* __restrict__ q,
    const f16* __restrict__ B1, const float* __restrict__ bias1,
    f16* __restrict__ X) {
  __shared__ f16 Al[128][40];
  __shared__ f16 Bl[256][40];
  const int tid = threadIdx.x;
  const int lane = tid & 63, wid = tid >> 6;
  const int wm = wid & 1, wn = wid >> 1;
  const int row0 = blockIdx.x * 128;
  const int l15 = lane & 15, l4 = lane >> 4;
  f32x4 acc[4][4];
#pragma unroll
  for (int i = 0; i < 4; i++)
#pragma unroll
    for (int j = 0; j < 4; j++) acc[i][j] = (f32x4){0.f, 0.f, 0.f, 0.f};

  const int arow = tid >> 2, aseg = tid & 3;
  const int brow = tid >> 1, bh = tid & 1;

  for (int k0 = 0; k0 < INDIM; k0 += 32) {
    const float* qp = q + (size_t)(row0 + arow) * INDIM + k0 + aseg * 8;
    f32x4 a0 = *(const f32x4*)qp;
    f32x4 a1 = *(const f32x4*)(qp + 4);
    f16x8 av;
#pragma unroll
    for (int i = 0; i < 4; i++) { av[i] = (f16)a0[i]; av[4 + i] = (f16)a1[i]; }
    const f16* bp = B1 + brow * INDIM + k0 + bh * 16;
    f16x8 bv0 = *(const f16x8*)bp;
    f16x8 bv1 = *(const f16x8*)(bp + 8);
    __syncthreads();
    *(f16x8*)&Al[arow][aseg * 8] = av;
    *(f16x8*)&Bl[brow][bh * 16] = bv0;
    *(f16x8*)&Bl[brow][bh * 16 + 8] = bv1;
    __syncthreads();
#pragma unroll
    for (int kk = 0; kk < 2; kk++) {
      const int kc = kk * 16 + 4 * l4;
      f16x4 af[4], bf[4];
#pragma unroll
      for (int mi = 0; mi < 4; mi++) af[mi] = *(const f16x4*)&Al[wm * 64 + mi * 16 + l15][kc];
#pragma unroll
      for (int ni = 0; ni < 4; ni++) bf[ni] = *(const f16x4*)&Bl[wn * 64 + ni * 16 + l15][kc];
#pragma unroll
      for (int mi = 0; mi < 4; mi++)
#pragma unroll
        for (int ni = 0; ni < 4; ni++)
          acc[mi][ni] = mfma16(af[mi], bf[ni], acc[mi][ni]);
    }
  }
#pragma unroll
  for (int ni = 0; ni < 4; ni++) {
    const int col = wn * 64 + ni * 16 + l15;
    const float bs = bias1[col];
#pragma unroll
    for (int mi = 0; mi < 4; mi++) {
      const int rb = row0 + wm * 64 + mi * 16 + 4 * l4;
#pragma unroll
      for (int j = 0; j < 4; j++)
        X[(size_t)(rb + j) * N1 + col] = (f16)(acc[mi][ni][j] + bs);
    }
  }
}

// ---------------- middle: softmaxes -> sparse-coded A2 [65536][288] f16 ----
__global__ __launch_bounds__(256) void k_mid(const f16* __restrict__ X,
    const int* __restrict__ cidx, const float* __restrict__ catk,
    f16* __restrict__ A2) {
  const int lane = threadIdx.x & 63;
  const int w = threadIdx.x >> 6;
  const int rb = blockIdx.x * 32 + w * 8;
  for (int r = 0; r < 8; r++) {
    const int row = rb + r;
    const f16* Xr = X + (size_t)row * N1;
    float bq = (float)Xr[lane];
    float cq = (float)Xr[64 + lane];
    float s0 = (float)Xr[128 + lane];
    float s1 = (lane < MSZ - 64) ? (float)Xr[192 + lane] : 0.f;
    float nb = bq * bq;
#pragma unroll
    for (int o = 32; o; o >>= 1) nb += __shfl_xor(nb, o, 64);
    const float rinv = 1.f / fmaxf(sqrtf(nb), 1e-8f);
    float v0 = s0 * rinv;
    float v1 = (lane < MSZ - 64) ? s1 * rinv : -1e30f;
    float mx = fmaxf(v0, v1);
#pragma unroll
    for (int o = 32; o; o >>= 1) mx = fmaxf(mx, __shfl_xor(mx, o, 64));
    float e0 = __expf(v0 - mx);
    float e1 = (lane < MSZ - 64) ? __expf(v1 - mx) : 0.f;
    float es = e0 + e1;
#pragma unroll
    for (int o = 32; o; o >>= 1) es += __shfl_xor(es, o, 64);
    const float isum = 1.f / es;
    const float a0 = e0 * isum, a1v = e1 * isum;

    const int ci = cidx[row];
    const float* kp = catk + (size_t)ci * (CKSZ * MD);
    float sc0, sc1, sc2, sc3, sc4;
    {
      float t0 = cq * kp[0 * MD + lane];
      float t1 = cq * kp[1 * MD + lane];
      float t2 = cq * kp[2 * MD + lane];
      float t3 = cq * kp[3 * MD + lane];
      float t4 = cq * kp[4 * MD + lane];
#pragma unroll
      for (int o = 32; o; o >>= 1) {
        t0 += __shfl_xor(t0, o, 64); t1 += __shfl_xor(t1, o, 64);
        t2 += __shfl_xor(t2, o, 64); t3 += __shfl_xor(t3, o, 64);
        t4 += __shfl_xor(t4, o, 64);
      }
      sc0 = t0; sc1 = t1; sc2 = t2; sc3 = t3; sc4 = t4;
    }
    float m5 = fmaxf(fmaxf(fmaxf(sc0, sc1), fmaxf(sc2, sc3)), sc4);
    float ce0 = __expf(sc0 - m5), ce1 = __expf(sc1 - m5), ce2 = __expf(sc2 - m5),
          ce3 = __expf(sc3 - m5), ce4 = __expf(sc4 - m5);
    const float ics = 1.f / (ce0 + ce1 + ce2 + ce3 + ce4);
    const int cbase = CKSZ * ci;
    f16* Ar = A2 + (size_t)row * KK2;
    // value at category-offset oo (position-100), 0 elsewhere
    auto catv = [&](int oo) -> float {
      float v = 0.f;
      v = (oo == cbase + 0) ? ce0 * ics : v;
      v = (oo == cbase + 1) ? ce1 * ics : v;
      v = (oo == cbase + 2) ? ce2 * ics : v;
      v = (oo == cbase + 3) ? ce3 * ics : v;
      v = (oo == cbase + 4) ? ce4 * ics : v;
      return v;
    };
    Ar[lane] = (f16)a0;
    { int p = 64 + lane;  Ar[p] = (f16)((p < MSZ) ? a1v : catv(p - MSZ)); }
    { int p = 128 + lane; Ar[p] = (f16)catv(p - MSZ); }
    { int p = 192 + lane; Ar[p] = (f16)catv(p - MSZ); }
    if (lane < 32) { int p = 256 + lane; Ar[p] = (f16)catv(p - MSZ); }
  }
}

// ---------------- GEMM2: out = A2 @ B2T^T + b_out (M=65536,K=288,N=512) ----
__global__ __launch_bounds__(512) void k_gemm2(const f16* __restrict__ A2,
    const f16* __restrict__ B2T, const float* __restrict__ bout,
    float* __restrict__ out) {
  __shared__ f16 Al[128][40];
  __shared__ f16 Bl[256][40];
  const int tid = threadIdx.x;
  const int lane = tid & 63, wid = tid >> 6;
  const int wm = wid & 1, wn = wid >> 1;
  const int row0 = blockIdx.x * 128;
  const int col0 = blockIdx.y * 256;
  const int l15 = lane & 15, l4 = lane >> 4;
  f32x4 acc[4][4];
#pragma unroll
  for (int i = 0; i < 4; i++)
#pragma unroll
    for (int j = 0; j < 4; j++) acc[i][j] = (f32x4){0.f, 0.f, 0.f, 0.f};

  const int arow = tid >> 2, aseg = tid & 3;
  const int brow = tid >> 1, bh = tid & 1;

  for (int k0 = 0; k0 < KK2; k0 += 32) {
    const f16* ap = A2 + (size_t)(row0 + arow) * KK2 + k0 + aseg * 8;
    f16x8 av = *(const f16x8*)ap;
    const f16* bp = B2T + (size_t)(col0 + brow) * KK2 + k0 + bh * 16;
    f16x8 bv0 = *(const f16x8*)bp;
    f16x8 bv1 = *(const f16x8*)(bp + 8);
    __syncthreads();
    *(f16x8*)&Al[arow][aseg * 8] = av;
    *(f16x8*)&Bl[brow][bh * 16] = bv0;
    *(f16x8*)&Bl[brow][bh * 16 + 8] = bv1;
    __syncthreads();
#pragma unroll
    for (int kk = 0; kk < 2; kk++) {
      const int kc = kk * 16 + 4 * l4;
      f16x4 af[4], bf[4];
#pragma unroll
      for (int mi = 0; mi < 4; mi++) af[mi] = *(const f16x4*)&Al[wm * 64 + mi * 16 + l15][kc];
#pragma unroll
      for (int ni = 0; ni < 4; ni++) bf[ni] = *(const f16x4*)&Bl[wn * 64 + ni * 16 + l15][kc];
#pragma unroll
      for (int mi = 0; mi < 4; mi++)
#pragma unroll
        for (int ni = 0; ni < 4; ni++)
          acc[mi][ni] = mfma16(af[mi], bf[ni], acc[mi][ni]);
    }
  }
#pragma unroll
  for (int ni = 0; ni < 4; ni++) {
    const int col = col0 + wn * 64 + ni * 16 + l15;
    const float bs = bout[col];
#pragma unroll
    for (int mi = 0; mi < 4; mi++) {
      const int rb = row0 + wm * 64 + mi * 16 + 4 * l4;
#pragma unroll
      for (int j = 0; j < 4; j++)
        out[(size_t)(rb + j) * ODIM + col] = acc[mi][ni][j] + bs;
    }
  }
}

extern "C" void kernel_launch(void* const* d_in, const int* in_sizes, int n_in,
                              void* d_out, int out_size, void* d_ws, size_t ws_size,
                              hipStream_t stream) {
  const float* query = (const float*)d_in[0];
  const int*   cidx  = (const int*)d_in[1];
  const float* Wb    = (const float*)d_in[2];
  const float* bb    = (const float*)d_in[3];
  const float* Wc    = (const float*)d_in[4];
  const float* bc    = (const float*)d_in[5];
  const float* bkeys = (const float*)d_in[6];
  const float* bvals = (const float*)d_in[7];
  const float* ckeys = (const float*)d_in[8];
  const float* cvals = (const float*)d_in[9];
  const float* Wo    = (const float*)d_in[10];
  const float* bo    = (const float*)d_in[11];
  float* out = (float*)d_out;

  char* ws = (char*)d_ws;
  size_t off = 0;
  f16* X  = (f16*)(ws + off); off += (size_t)BATCH * N1 * 2;    // 33.55 MB
  f16* A2 = (f16*)(ws + off); off += (size_t)BATCH * KK2 * 2;   // 37.75 MB
  f16* B1 = (f16*)(ws + off); off += (size_t)N1 * INDIM * 2;    // 0.26 MB
  float* bias1 = (float*)(ws + off); off += (size_t)N1 * 4;
  f16* B2T = (f16*)(ws + off); off += (size_t)ODIM * KK2 * 2;   // 0.29 MB

  k_prep1<<<dim3((N1 * INDIM) / 256), 256, 0, stream>>>(Wb, bb, Wc, bc, bkeys, B1, bias1);
  k_prep2<<<dim3((ODIM * KK2 + 255) / 256), 256, 0, stream>>>(bvals, cvals, Wo, B2T);
  k_gemm1<<<dim3(BATCH / 128), 512, 0, stream>>>(query, B1, bias1, X);
  k_mid<<<dim3(BATCH / 32), 256, 0, stream>>>(X, cidx, ckeys, A2);
  k_gemm2<<<dim3(BATCH / 128, ODIM / 256), 512, 0, stream>>>(A2, B2T, bo, out);
}